// Round 11
// baseline (136.271 us; speedup 1.0000x reference)
//
#include <hip/hip_runtime.h>

#define N_NODES 10000
#define N_EDGES 100000
#define SLOTS 40   // max degree bound; Poisson(10), P(deg>=40) ~ 1e-12

typedef __attribute__((ext_vector_type(8))) _Float16 f16x8;
typedef __attribute__((ext_vector_type(2))) _Float16 f16x2;
typedef __attribute__((ext_vector_type(4))) float f32x4;

static __device__ inline f16x2 pkrtz(float a, float b) {
    auto t = __builtin_amdgcn_cvt_pkrtz(a, b);
    union { decltype(t) x; f16x2 y; } u;
    u.x = t;
    return u.y;
}
static __device__ inline unsigned short f16u(float x) {
    union { _Float16 h; unsigned short s; } u;
    u.h = (_Float16)x;
    return u.s;
}
static __device__ inline float f16f(unsigned short us) {
    union { unsigned short s; _Float16 h; } u;
    u.s = us;
    return (float)u.h;
}
static __device__ inline f16x8 cvt8h(const float* f) {
    f16x8 r; f16x2* rp = (f16x2*)&r;
#pragma unroll
    for (int i = 0; i < 4; ++i) rp[i] = pkrtz(f[2 * i], f[2 * i + 1]);
    return r;
}
static __device__ inline f16x8 scale8(f16x2 h2, f16x8 x) {
    f16x8 r; f16x2* rp = (f16x2*)&r; f16x2* xp = (f16x2*)&x;
#pragma unroll
    for (int i = 0; i < 4; ++i) rp[i] = h2 * xp[i];
    return r;
}
// dt8 = xvx*y0 + xvy*y1 + xvz*y2, all packed f16
static __device__ inline f16x8 dot3(f16x8 xx, f16x8 xy, f16x8 xz, f32x4 ea) {
    _Float16 y0 = (_Float16)ea.y, y1 = (_Float16)ea.z, y2 = (_Float16)ea.w;
    f16x2 y0_2 = {y0, y0}, y1_2 = {y1, y1}, y2_2 = {y2, y2};
    f16x8 r; f16x2* rp = (f16x2*)&r;
    f16x2* xp = (f16x2*)&xx; f16x2* yp = (f16x2*)&xy; f16x2* zp = (f16x2*)&xz;
#pragma unroll
    for (int i = 0; i < 4; ++i)
        rp[i] = xp[i] * y0_2 + yp[i] * y1_2 + zp[i] * y2_2;
    return r;
}

// ---------------------------------------------------------------------------
// Prep kernel: 64 blocks x 1024 threads.
//  - Wc / WB folds + xf table as before.
//  - NEW: elist build — receiver->edge-id lists via distributed atomics
//    (cnt zeroed by hipMemsetAsync BEFORE this kernel). Slots are thus
//    assigned here, making the edge kernel fully deterministic (no atomics).
// ---------------------------------------------------------------------------
__global__ __launch_bounds__(1024) void prep_kernel(
    const float* __restrict__ Wgen, const float* __restrict__ L1s,
    const float* __restrict__ L1v, const float* __restrict__ WS0,
    const float* __restrict__ WS1, const float* __restrict__ L2s,
    const float* __restrict__ L2v, const float* __restrict__ node_feats,
    const int* __restrict__ edge_index, unsigned short* __restrict__ Wc,
    unsigned short* __restrict__ WB0, unsigned short* __restrict__ WB1,
    unsigned short* __restrict__ xf, int* __restrict__ cnt,
    int* __restrict__ elist) {
    const float S = 1.0f / 128.0f;
    int tid = blockIdx.x * 1024 + threadIdx.x;   // 0..65535
    // elist build: slot assignment for each edge (cnt pre-zeroed by memset)
    for (int e = tid; e < N_EDGES; e += 65536) {
        int r = edge_index[N_EDGES + e];
        int k = atomicAdd(&cnt[r], 1);
        elist[r * SLOTS + k] = e;
    }
    if (tid < 40000) {                           // xf fill: one (n,q) per thread
        int n = tid >> 2, qq = tid & 3;
        const float* g = node_feats + n * 128;
        unsigned short* dst = xf + (size_t)tid * 32;
#pragma unroll
        for (int j = 0; j < 8; ++j) dst[j] = f16u(g[qq * 8 + j]);
#pragma unroll
        for (int c = 0; c < 3; ++c)
#pragma unroll
            for (int j = 0; j < 8; ++j)
                dst[8 + c * 8 + j] = f16u(g[32 + qq * 24 + j * 3 + c]);
    }
    if (tid < 32768) {
        int j = tid & 7;
        int lane = (tid >> 3) & 63;
        int ks = (tid >> 9) & 7;
        int nt = tid >> 12;
        int col = nt * 16 + (lane & 15);
        int u = (lane >> 4) * 8 + j;
        int r = ks;
        int p, c2;
        const float* M;
        float sc = S;
        if (col < 32)      { p = 0; M = L1s; c2 = col; }
        else if (col < 64) { p = 1; M = L1v; c2 = col - 32; }
        else if (col < 96) { p = 2; M = L1v; c2 = col - 64; }
        else               { p = 3; M = L1s; c2 = col - 96; sc = S * 0.57735026918962576f; }
        const float* wg = Wgen + r * 4096 + p * 1024 + u * 32;
        float acc = 0.f;
#pragma unroll
        for (int w = 0; w < 32; ++w) acc += wg[w] * M[w * 32 + c2];
        Wc[tid] = f16u(acc * sc);
    } else {
        int idx = tid - 32768;
        int table = idx >> 14;
        int r14 = idx & 16383;
        int j = r14 & 7;
        int lane = (r14 >> 3) & 63;
        int ks = (r14 >> 9) & 15;
        int k = ks * 32 + (lane >> 4) * 8 + j;
        int u = k >> 4, v = k & 15;
        int w = ((r14 >> 13) & 1) * 16 + (lane & 15);
        const float* WS = table ? WS1 : WS0;
        const float* L2 = table ? L2v : L2s;
        const float* src = WS + u * 512 + v * 32;
        float acc = 0.f;
#pragma unroll
        for (int x = 0; x < 32; ++x) acc += src[x] * L2[x * 32 + w];
        unsigned short val = f16u(acc * S);
        if (table) WB1[r14] = val; else WB0[r14] = val;
    }
}

// ---------------------------------------------------------------------------
// Edge kernel v13: BLOCK-SPECIALIZED HALVES for 2x occupancy.
//  - The 64KB W-table capped residency at 2 blocks/CU (2 waves/SIMD) — the
//    invariant behind 3 rounds of flat results. Split by output:
//      half0 (blocks with bid%8<3):  tables {WA,WD} -> ms   (32KB LDS)
//      half1 (blocks with bid%8>=3): tables {WB,WC} -> mv   (32KB LDS)
//    -> 4 blocks/CU, 12-16 waves/CU.
//  - Msg is EDGE-INDEXED (row = edge id, comp-major [ms32|mvx32|mvy32|mvz32]),
//    so no atomics / slot machinery in edge at all; receiver mapping lives in
//    prep's elist. Msg writes are near-sequential.
//  - kept: 2-deep snd prefetch, sEA strip, static stride per half.
// ---------------------------------------------------------------------------
__global__ __launch_bounds__(256) void edge_kernel(
    const unsigned short* __restrict__ xf, const float* __restrict__ edge_attrs,
    const float* __restrict__ edge_feats, const int* __restrict__ edge_index,
    const unsigned short* __restrict__ Wc, unsigned short* __restrict__ Msg) {
    __shared__ f16x8 sW[2048];      // 32 KB: this half's 4 tables
    __shared__ f32x4 sEA[4][16];    // per-wave edge_attrs strip

    const int bid = blockIdx.x;
    const bool h0 = (bid & 7) < 3;
    {
        int g0, g1, g2, g3;
        if (h0) { g0 = 0; g1 = 1; g2 = 6; g3 = 7; }
        else    { g0 = 2; g1 = 3; g2 = 4; g3 = 5; }
        const f16x8* src = (const f16x8*)Wc;
        for (int i = threadIdx.x; i < 2048; i += 256) {
            int slot = i >> 9, rem = i & 511;
            int gt = slot == 0 ? g0 : slot == 1 ? g1 : slot == 2 ? g2 : g3;
            sW[i] = src[(gt << 9) + rem];
        }
    }
    __syncthreads();

    const int lane = threadIdx.x & 63;
    const int m = lane & 15, q = lane >> 4;
    const int wv = threadIdx.x >> 6;
    const int NT = N_EDGES / 16;
    const int rank = h0 ? ((bid >> 3) * 3 + (bid & 7))
                        : ((bid >> 3) * 5 + ((bid & 7) - 3));
    const int nblk = h0 ? 384 : 640;
    const int stride = nblk * 4;
    int tile = rank * 4 + wv;
    if (tile >= NT) return;

    float efC[8];
    f32x4 eaC;

    if (h0) {
        // ================= HALF 0: ms = ys*A + D (tables WA, WD) ===========
        f16x8 xs8, dt8;
        {
            int e = tile * 16 + m;
            int snd = edge_index[e];
            eaC = *(const f32x4*)(edge_attrs + e * 4);
            const f16x8* gx = (const f16x8*)(xf + (size_t)(snd * 4 + q) * 32);
            xs8 = gx[0];
            dt8 = dot3(gx[1], gx[2], gx[3], eaC);
            *(f32x4*)&efC[0] = *(const f32x4*)(edge_feats + e * 8);
            *(f32x4*)&efC[4] = *(const f32x4*)(edge_feats + e * 8 + 4);
        }
        int snd1 = 0;
        {
            int t1 = tile + stride;
            if (t1 < NT) snd1 = edge_index[t1 * 16 + m];
        }
        while (tile < NT) {
            const int tn = tile + stride;
            const bool hasN = tn < NT;
            const int t2 = tile + 2 * stride;

            if (lane < 16) sEA[wv][lane] = eaC;

            f16x8 xsN, xvxN, xvyN, xvzN;
            float efN[8];
            f32x4 eaN;
            if (hasN) {
                int en = tn * 16 + m;
                const f16x8* gN = (const f16x8*)(xf + (size_t)(snd1 * 4 + q) * 32);
                xsN = gN[0]; xvxN = gN[1]; xvyN = gN[2]; xvzN = gN[3];
                *(f32x4*)&efN[0] = *(const f32x4*)(edge_feats + en * 8);
                *(f32x4*)&efN[4] = *(const f32x4*)(edge_feats + en * 8 + 4);
                eaN = *(const f32x4*)(edge_attrs + en * 4);
            }
            int snd2 = 0;
            if (t2 < NT) snd2 = edge_index[t2 * 16 + m];

            f32x4 z = {0.f, 0.f, 0.f, 0.f};
            f32x4 fA[2] = {z, z}, fD[2] = {z, z};
#pragma unroll
            for (int ks = 0; ks < 8; ++ks) {
                _Float16 h = (_Float16)efC[ks];
                f16x2 h2 = {h, h};
                f16x8 aS = scale8(h2, xs8);
                fA[0] = __builtin_amdgcn_mfma_f32_16x16x32_f16(aS, sW[(0 * 8 + ks) * 64 + lane], fA[0], 0, 0, 0);
                fA[1] = __builtin_amdgcn_mfma_f32_16x16x32_f16(aS, sW[(1 * 8 + ks) * 64 + lane], fA[1], 0, 0, 0);
                f16x8 aD = scale8(h2, dt8);
                fD[0] = __builtin_amdgcn_mfma_f32_16x16x32_f16(aD, sW[(2 * 8 + ks) * 64 + lane], fD[0], 0, 0, 0);
                fD[1] = __builtin_amdgcn_mfma_f32_16x16x32_f16(aD, sW[(3 * 8 + ks) * 64 + lane], fD[1], 0, 0, 0);
            }
#pragma unroll
            for (int t4 = 0; t4 < 4; ++t4) {
                float ysr = sEA[wv][q * 4 + t4].x;
                size_t row = (size_t)(tile * 16 + q * 4 + t4) * 128;
#pragma unroll
                for (int nt = 0; nt < 2; ++nt)
                    Msg[row + nt * 16 + m] = f16u(ysr * fA[nt][t4] + fD[nt][t4]);
            }
            tile = tn;
            if (hasN) {
                xs8 = xsN;
                dt8 = dot3(xvxN, xvyN, xvzN, eaN);
#pragma unroll
                for (int j = 0; j < 8; ++j) efC[j] = efN[j];
                eaC = eaN;
                snd1 = snd2;
            }
        }
    } else {
        // ============ HALF 1: mv_c = y_c*B + ys*C_c (tables WB, WC) ========
        f16x8 xs8, xv8[3];
        {
            int e = tile * 16 + m;
            int snd = edge_index[e];
            eaC = *(const f32x4*)(edge_attrs + e * 4);
            const f16x8* gx = (const f16x8*)(xf + (size_t)(snd * 4 + q) * 32);
            xs8 = gx[0]; xv8[0] = gx[1]; xv8[1] = gx[2]; xv8[2] = gx[3];
            *(f32x4*)&efC[0] = *(const f32x4*)(edge_feats + e * 8);
            *(f32x4*)&efC[4] = *(const f32x4*)(edge_feats + e * 8 + 4);
        }
        int snd1 = 0;
        {
            int t1 = tile + stride;
            if (t1 < NT) snd1 = edge_index[t1 * 16 + m];
        }
        while (tile < NT) {
            const int tn = tile + stride;
            const bool hasN = tn < NT;
            const int t2 = tile + 2 * stride;

            if (lane < 16) sEA[wv][lane] = eaC;

            f16x8 xsN, xvxN, xvyN, xvzN;
            float efN[8];
            f32x4 eaN;
            if (hasN) {
                int en = tn * 16 + m;
                const f16x8* gN = (const f16x8*)(xf + (size_t)(snd1 * 4 + q) * 32);
                xsN = gN[0]; xvxN = gN[1]; xvyN = gN[2]; xvzN = gN[3];
                *(f32x4*)&efN[0] = *(const f32x4*)(edge_feats + en * 8);
                *(f32x4*)&efN[4] = *(const f32x4*)(edge_feats + en * 8 + 4);
                eaN = *(const f32x4*)(edge_attrs + en * 4);
            }
            int snd2 = 0;
            if (t2 < NT) snd2 = edge_index[t2 * 16 + m];

            f32x4 z = {0.f, 0.f, 0.f, 0.f};
            f32x4 fB[2] = {z, z};
            f32x4 fC[3][2] = {{z, z}, {z, z}, {z, z}};
#pragma unroll
            for (int ks = 0; ks < 8; ++ks) {
                _Float16 h = (_Float16)efC[ks];
                f16x2 h2 = {h, h};
                f16x8 aS = scale8(h2, xs8);
                fB[0] = __builtin_amdgcn_mfma_f32_16x16x32_f16(aS, sW[(0 * 8 + ks) * 64 + lane], fB[0], 0, 0, 0);
                fB[1] = __builtin_amdgcn_mfma_f32_16x16x32_f16(aS, sW[(1 * 8 + ks) * 64 + lane], fB[1], 0, 0, 0);
                f16x8 bc0 = sW[(2 * 8 + ks) * 64 + lane];
                f16x8 bc1 = sW[(3 * 8 + ks) * 64 + lane];
#pragma unroll
                for (int c = 0; c < 3; ++c) {
                    f16x8 a = scale8(h2, xv8[c]);
                    fC[c][0] = __builtin_amdgcn_mfma_f32_16x16x32_f16(a, bc0, fC[c][0], 0, 0, 0);
                    fC[c][1] = __builtin_amdgcn_mfma_f32_16x16x32_f16(a, bc1, fC[c][1], 0, 0, 0);
                }
            }
#pragma unroll
            for (int t4 = 0; t4 < 4; ++t4) {
                f32x4 ea4 = sEA[wv][q * 4 + t4];
                float ysr = ea4.x;
                float yr[3] = {ea4.y, ea4.z, ea4.w};
                size_t row = (size_t)(tile * 16 + q * 4 + t4) * 128;
#pragma unroll
                for (int nt = 0; nt < 2; ++nt) {
                    float pb = fB[nt][t4];
#pragma unroll
                    for (int c = 0; c < 3; ++c)
                        Msg[row + 32 + c * 32 + nt * 16 + m] =
                            f16u(yr[c] * pb + ysr * fC[c][nt][t4]);
                }
            }
            tile = tn;
            if (hasN) {
                xs8 = xsN; xv8[0] = xvxN; xv8[1] = xvyN; xv8[2] = xvzN;
#pragma unroll
                for (int j = 0; j < 8; ++j) efC[j] = efN[j];
                eaC = eaN;
                snd1 = snd2;
            }
        }
    }
}

// ---------------------------------------------------------------------------
// Node kernel: gather via elist indirection (deg from cnt). 16 unconditional
// Msg-row loads with clamped edge ids + predicated accumulate. Msg rows are
// comp-major [ms|mvx|mvy|mvz] so sM fill is a direct linear copy.
// ---------------------------------------------------------------------------
__global__ __launch_bounds__(256) void node_kernel(
    const float* __restrict__ node_attrs, const unsigned short* __restrict__ Msg,
    const int* __restrict__ cnt, const int* __restrict__ elist,
    const unsigned short* __restrict__ WB0, const unsigned short* __restrict__ WB1,
    float* __restrict__ out) {
    __shared__ float sM[16][129];
    __shared__ float sAt[16][17];
    int n0 = blockIdx.x * 16;

    int nl = threadIdx.x >> 4;
    int cg = threadIdx.x & 15;
    int n = n0 + nl;
    int deg = cnt[n];
    const int* el = elist + n * SLOTS;
    float acc[8];
#pragma unroll
    for (int j = 0; j < 8; ++j) acc[j] = 0.f;
    {
        int4 e4[4];
#pragma unroll
        for (int i = 0; i < 4; ++i) e4[i] = *(const int4*)(el + i * 4);
        const int* ei = (const int*)e4;
        f32x4 r[16];
#pragma unroll
        for (int i = 0; i < 16; ++i) {
            int e = (i < deg) ? ei[i] : 0;   // clamp: unwritten slots are poison
            r[i] = *(const f32x4*)(Msg + (size_t)e * 128 + cg * 8);
        }
#pragma unroll
        for (int i = 0; i < 16; ++i) {
            if (i < deg) {
                const unsigned short* us = (const unsigned short*)&r[i];
#pragma unroll
                for (int j = 0; j < 8; ++j) acc[j] += f16f(us[j]);
            }
        }
    }
    for (int s = 16; s < deg; ++s) {   // rare deg>16 tail
        int e = el[s];
        f32x4 raw = *(const f32x4*)(Msg + (size_t)e * 128 + cg * 8);
        const unsigned short* us = (const unsigned short*)&raw;
#pragma unroll
        for (int j = 0; j < 8; ++j) acc[j] += f16f(us[j]);
    }
#pragma unroll
    for (int j = 0; j < 8; ++j) sM[nl][cg * 8 + j] = acc[j];
    sAt[nl][cg] = node_attrs[n * 16 + cg];
    __syncthreads();

    int p = threadIdx.x >> 6;
    int lane = threadIdx.x & 63;
    int m = lane & 15, q = lane >> 4;
    const unsigned short* WB = (p == 0) ? WB0 : WB1;
    int chb = p * 32;
    f32x4 z = {0.f, 0.f, 0.f, 0.f};
    f32x4 D0 = z, D1 = z;
#pragma unroll
    for (int ks = 0; ks < 16; ++ks) {
        int kb = ks * 32 + q * 8;
        float t[8];
#pragma unroll
        for (int j = 0; j < 8; ++j) {
            int k = kb + j;
            t[j] = sM[m][chb + (k >> 4)] * sAt[m][k & 15];
        }
        f16x8 a = cvt8h(t);
        f16x8 b0 = *(const f16x8*)(WB + (ks * 64 + lane) * 8);
        f16x8 b1 = *(const f16x8*)(WB + ((16 + ks) * 64 + lane) * 8);
        D0 = __builtin_amdgcn_mfma_f32_16x16x32_f16(a, b0, D0, 0, 0, 0);
        D1 = __builtin_amdgcn_mfma_f32_16x16x32_f16(a, b1, D1, 0, 0, 0);
    }

#pragma unroll
    for (int t4 = 0; t4 < 4; ++t4) {
        int nl2 = q * 4 + t4;
        int nn = n0 + nl2;
        if (p == 0) {
            out[nn * 128 + m]      = sM[nl2][m] + D0[t4];
            out[nn * 128 + 16 + m] = sM[nl2][16 + m] + D1[t4];
        } else {
            int i = p - 1;
            out[nn * 128 + 32 + m * 3 + i]        = sM[nl2][chb + m] + D0[t4];
            out[nn * 128 + 32 + (16 + m) * 3 + i] = sM[nl2][chb + 16 + m] + D1[t4];
        }
    }
}

extern "C" void kernel_launch(void* const* d_in, const int* in_sizes, int n_in,
                              void* d_out, int out_size, void* d_ws, size_t ws_size,
                              hipStream_t stream) {
    (void)in_sizes; (void)n_in; (void)out_size; (void)ws_size;
    const float* node_attrs = (const float*)d_in[0];
    const float* node_feats = (const float*)d_in[1];
    const float* edge_attrs = (const float*)d_in[2];
    const float* edge_feats = (const float*)d_in[3];
    const int*   edge_index = (const int*)d_in[4];
    const float* Wgen = (const float*)d_in[5];
    const float* L1s  = (const float*)d_in[6];
    const float* L1v  = (const float*)d_in[7];
    const float* WS0  = (const float*)d_in[8];
    const float* WS1  = (const float*)d_in[9];
    const float* L2s  = (const float*)d_in[10];
    const float* L2v  = (const float*)d_in[11];
    float* out = (float*)d_out;
    char* ws = (char*)d_ws;

    // Msg: N_EDGES rows x 128 f16 (edge-indexed, comp-major) = 25,600,000 B
    unsigned short* Msg = (unsigned short*)ws;
    unsigned short* Wc  = (unsigned short*)(ws + 25600000);    //    65,536
    unsigned short* WB0 = (unsigned short*)(ws + 25665536);    //    32,768
    unsigned short* WB1 = (unsigned short*)(ws + 25698304);    //    32,768
    int* cnt   = (int*)(ws + 25731072);                        //    40,000
    int* elist = (int*)(ws + 25771072);                        // 1,600,000
    unsigned short* xf = (unsigned short*)(ws + 27371072);     // 2,560,000

    hipMemsetAsync(cnt, 0, N_NODES * sizeof(int), stream);
    prep_kernel<<<64, 1024, 0, stream>>>(Wgen, L1s, L1v, WS0, WS1, L2s, L2v,
                                         node_feats, edge_index, Wc, WB0, WB1,
                                         xf, cnt, elist);
    edge_kernel<<<1024, 256, 0, stream>>>(xf, edge_attrs, edge_feats,
                                          edge_index, Wc, Msg);
    node_kernel<<<625, 256, 0, stream>>>(node_attrs, Msg, cnt, elist,
                                         WB0, WB1, out);
}

// Round 12
// 133.408 us; speedup vs baseline: 1.0215x; 1.0215x over previous
//
#include <hip/hip_runtime.h>

#define N_NODES 10000
#define N_EDGES 100000
#define SLOTS 40   // max degree bound; Poisson(10), P(deg>=40) ~ 1e-12

typedef __attribute__((ext_vector_type(8))) _Float16 f16x8;
typedef __attribute__((ext_vector_type(2))) _Float16 f16x2;
typedef __attribute__((ext_vector_type(4))) float f32x4;

static __device__ inline f16x2 pkrtz(float a, float b) {
    auto t = __builtin_amdgcn_cvt_pkrtz(a, b);
    union { decltype(t) x; f16x2 y; } u;
    u.x = t;
    return u.y;
}
static __device__ inline unsigned short f16u(float x) {
    union { _Float16 h; unsigned short s; } u;
    u.h = (_Float16)x;
    return u.s;
}
static __device__ inline float f16f(unsigned short us) {
    union { unsigned short s; _Float16 h; } u;
    u.s = us;
    return (float)u.h;
}
static __device__ inline f16x8 cvt8h(const float* f) {
    f16x8 r; f16x2* rp = (f16x2*)&r;
#pragma unroll
    for (int i = 0; i < 4; ++i) rp[i] = pkrtz(f[2 * i], f[2 * i + 1]);
    return r;
}
static __device__ inline f16x8 scale8(f16x2 h2, f16x8 x) {
    f16x8 r; f16x2* rp = (f16x2*)&r; f16x2* xp = (f16x2*)&x;
#pragma unroll
    for (int i = 0; i < 4; ++i) rp[i] = h2 * xp[i];
    return r;
}
static __device__ inline int pack2(float a, float b) {
    union { f16x2 h; int i; } u;
    u.h = pkrtz(a, b);
    return u.i;
}
// dt8 = xvx*y0 + xvy*y1 + xvz*y2, all packed f16
static __device__ inline f16x8 dot3(f16x8 xx, f16x8 xy, f16x8 xz, f32x4 ea) {
    _Float16 y0 = (_Float16)ea.y, y1 = (_Float16)ea.z, y2 = (_Float16)ea.w;
    f16x2 y0_2 = {y0, y0}, y1_2 = {y1, y1}, y2_2 = {y2, y2};
    f16x8 r; f16x2* rp = (f16x2*)&r;
    f16x2* xp = (f16x2*)&xx; f16x2* yp = (f16x2*)&xy; f16x2* zp = (f16x2*)&xz;
#pragma unroll
    for (int i = 0; i < 4; ++i)
        rp[i] = xp[i] * y0_2 + yp[i] * y1_2 + zp[i] * y2_2;
    return r;
}

// ---------------------------------------------------------------------------
// Prep kernel (R10's, unchanged): 64 blocks x 1024 threads.
// cnt zeroed here; Wc/WB folds + xf gather table (f16, L2-resident).
// ---------------------------------------------------------------------------
__global__ __launch_bounds__(1024) void prep_kernel(
    const float* __restrict__ Wgen, const float* __restrict__ L1s,
    const float* __restrict__ L1v, const float* __restrict__ WS0,
    const float* __restrict__ WS1, const float* __restrict__ L2s,
    const float* __restrict__ L2v, const float* __restrict__ node_feats,
    unsigned short* __restrict__ Wc, unsigned short* __restrict__ WB0,
    unsigned short* __restrict__ WB1, unsigned short* __restrict__ xf,
    int* __restrict__ cnt) {
    const float S = 1.0f / 128.0f;
    int tid = blockIdx.x * 1024 + threadIdx.x;   // 0..65535
    if (tid < N_NODES) cnt[tid] = 0;             // per-node slot counters
    if (tid < 40000) {                           // xf fill: one (n,q) per thread
        int n = tid >> 2, qq = tid & 3;
        const float* g = node_feats + n * 128;
        unsigned short* dst = xf + (size_t)tid * 32;
#pragma unroll
        for (int j = 0; j < 8; ++j) dst[j] = f16u(g[qq * 8 + j]);
#pragma unroll
        for (int c = 0; c < 3; ++c)
#pragma unroll
            for (int j = 0; j < 8; ++j)
                dst[8 + c * 8 + j] = f16u(g[32 + qq * 24 + j * 3 + c]);
    }
    if (tid < 32768) {
        int j = tid & 7;
        int lane = (tid >> 3) & 63;
        int ks = (tid >> 9) & 7;
        int nt = tid >> 12;
        int col = nt * 16 + (lane & 15);
        int u = (lane >> 4) * 8 + j;
        int r = ks;
        int p, c2;
        const float* M;
        float sc = S;
        if (col < 32)      { p = 0; M = L1s; c2 = col; }
        else if (col < 64) { p = 1; M = L1v; c2 = col - 32; }
        else if (col < 96) { p = 2; M = L1v; c2 = col - 64; }
        else               { p = 3; M = L1s; c2 = col - 96; sc = S * 0.57735026918962576f; }
        const float* wg = Wgen + r * 4096 + p * 1024 + u * 32;
        float acc = 0.f;
#pragma unroll
        for (int w = 0; w < 32; ++w) acc += wg[w] * M[w * 32 + c2];
        Wc[tid] = f16u(acc * sc);
    } else {
        int idx = tid - 32768;
        int table = idx >> 14;
        int r14 = idx & 16383;
        int j = r14 & 7;
        int lane = (r14 >> 3) & 63;
        int ks = (r14 >> 9) & 15;
        int k = ks * 32 + (lane >> 4) * 8 + j;
        int u = k >> 4, v = k & 15;
        int w = ((r14 >> 13) & 1) * 16 + (lane & 15);
        const float* WS = table ? WS1 : WS0;
        const float* L2 = table ? L2v : L2s;
        const float* src = WS + u * 512 + v * 32;
        float acc = 0.f;
#pragma unroll
        for (int x = 0; x < 32; ++x) acc += src[x] * L2[x * 32 + w];
        unsigned short val = f16u(acc * S);
        if (table) WB1[r14] = val; else WB0[r14] = val;
    }
}

// ---------------------------------------------------------------------------
// Edge kernel v14: EDGE-INDEXED Msg (row = edge id, deterministic) —
// 25.6 MB instead of 102 MB, so node's read traffic drops 4x.
//  - the slot atomic no longer addresses Msg: lane<16 publishes
//    elist[r*SLOTS+k]=e (fire-and-forget 4B store, latency hidden).
//    sSL strip + slot pipeline removed entirely.
//  - epilogue keeps R10's interleaved row layout -> 8x int2 stores/lane
//    (R11's 32x 2B stores regressed store-issue).
//  - else identical to R10: f16 xf gather, 2-deep idx prefetch, sEA strip.
// ---------------------------------------------------------------------------
__global__ __launch_bounds__(256) void edge_kernel(
    const unsigned short* __restrict__ xf, const float* __restrict__ edge_attrs,
    const float* __restrict__ edge_feats, const int* __restrict__ edge_index,
    const unsigned short* __restrict__ Wc, int* __restrict__ cnt,
    int* __restrict__ elist, unsigned short* __restrict__ Msg) {
    __shared__ f16x8 sW8[4096];     // 64 KB, B-fragment order (f16 bits)
    __shared__ f32x4 sEA[4][16];    // per-wave edge_attrs strip
    {
        const f16x8* src = (const f16x8*)Wc;
        for (int i = threadIdx.x; i < 4096; i += 256) sW8[i] = src[i];
    }
    __syncthreads();

    const int lane = threadIdx.x & 63;
    const int m = lane & 15, q = lane >> 4;
    const int wv = threadIdx.x >> 6;
    const int wave = (blockIdx.x * 256 + threadIdx.x) >> 6;
    const int stride = gridDim.x * 4;
    const int NT = N_EDGES / 16;

    int tile = wave;
    if (tile >= NT) return;

    f16x8 xs8, xv8[3], dt8;
    float efC[8];
    f32x4 eaC;

    // ---- prologue
    {
        int e = tile * 16 + m;
        int snd = edge_index[e];
        if (lane < 16) {
            int r = edge_index[N_EDGES + e];
            int k = atomicAdd(&cnt[r], 1);
            elist[r * SLOTS + k] = e;
        }
        const f16x8* gx = (const f16x8*)(xf + (size_t)(snd * 4 + q) * 32);
        xs8 = gx[0]; xv8[0] = gx[1]; xv8[1] = gx[2]; xv8[2] = gx[3];
        *(f32x4*)&efC[0] = *(const f32x4*)(edge_feats + e * 8);
        *(f32x4*)&efC[4] = *(const f32x4*)(edge_feats + e * 8 + 4);
        eaC = *(const f32x4*)(edge_attrs + e * 4);
        dt8 = dot3(xv8[0], xv8[1], xv8[2], eaC);
    }
    int snd1 = 0;
    {
        int t1 = tile + stride;
        if (t1 < NT) snd1 = edge_index[t1 * 16 + m];
    }

    while (tile < NT) {
        const int tn = tile + stride;
        const bool hasN = tn < NT;
        const int t2 = tile + 2 * stride;

        if (lane < 16) sEA[wv][lane] = eaC;

        // ---- prefetch tile+s state (in-register snd index, no dep wait)
        f16x8 xsN, xvxN, xvyN, xvzN;
        float efN[8];
        f32x4 eaN;
        if (hasN) {
            int en = tn * 16 + m;
            if (lane < 16) {
                int r = edge_index[N_EDGES + en];
                int k = atomicAdd(&cnt[r], 1);
                elist[r * SLOTS + k] = en;
            }
            const f16x8* gN = (const f16x8*)(xf + (size_t)(snd1 * 4 + q) * 32);
            xsN = gN[0]; xvxN = gN[1]; xvyN = gN[2]; xvzN = gN[3];
            *(f32x4*)&efN[0] = *(const f32x4*)(edge_feats + en * 8);
            *(f32x4*)&efN[4] = *(const f32x4*)(edge_feats + en * 8 + 4);
            eaN = *(const f32x4*)(edge_attrs + en * 4);
        }

        // ---- prefetch tile+2s snd index
        int snd2 = 0;
        if (t2 < NT) snd2 = edge_index[t2 * 16 + m];

        // ---- compute current tile (f16 packed A-builds)
        f32x4 z = {0.f, 0.f, 0.f, 0.f};
        f32x4 fA[2] = {z, z}, fB[2] = {z, z}, fD[2] = {z, z};
        f32x4 fC[3][2] = {{z, z}, {z, z}, {z, z}};

#pragma unroll
        for (int ks = 0; ks < 8; ++ks) {
            _Float16 h = (_Float16)efC[ks];
            f16x2 h2 = {h, h};
            {
                f16x8 a = scale8(h2, xs8);
                fA[0] = __builtin_amdgcn_mfma_f32_16x16x32_f16(a, sW8[(0 * 8 + ks) * 64 + lane], fA[0], 0, 0, 0);
                fA[1] = __builtin_amdgcn_mfma_f32_16x16x32_f16(a, sW8[(1 * 8 + ks) * 64 + lane], fA[1], 0, 0, 0);
                fB[0] = __builtin_amdgcn_mfma_f32_16x16x32_f16(a, sW8[(2 * 8 + ks) * 64 + lane], fB[0], 0, 0, 0);
                fB[1] = __builtin_amdgcn_mfma_f32_16x16x32_f16(a, sW8[(3 * 8 + ks) * 64 + lane], fB[1], 0, 0, 0);
            }
            {
                f16x8 bc0 = sW8[(4 * 8 + ks) * 64 + lane];
                f16x8 bc1 = sW8[(5 * 8 + ks) * 64 + lane];
#pragma unroll
                for (int c = 0; c < 3; ++c) {
                    f16x8 a = scale8(h2, xv8[c]);
                    fC[c][0] = __builtin_amdgcn_mfma_f32_16x16x32_f16(a, bc0, fC[c][0], 0, 0, 0);
                    fC[c][1] = __builtin_amdgcn_mfma_f32_16x16x32_f16(a, bc1, fC[c][1], 0, 0, 0);
                }
            }
            {
                f16x8 a = scale8(h2, dt8);
                fD[0] = __builtin_amdgcn_mfma_f32_16x16x32_f16(a, sW8[(6 * 8 + ks) * 64 + lane], fD[0], 0, 0, 0);
                fD[1] = __builtin_amdgcn_mfma_f32_16x16x32_f16(a, sW8[(7 * 8 + ks) * 64 + lane], fD[1], 0, 0, 0);
            }
        }

        // ---- epilogue: row = edge id (deterministic), interleaved layout,
        //      8x int2 stores per lane
#pragma unroll
        for (int t4 = 0; t4 < 4; ++t4) {
            f32x4 ea4 = sEA[wv][q * 4 + t4];
            float ysr = ea4.x, y0r = ea4.y, y1r = ea4.z, y2r = ea4.w;
            size_t row = (size_t)(tile * 16 + q * 4 + t4) * 128;
#pragma unroll
            for (int nt = 0; nt < 2; ++nt) {
                int col = nt * 16 + m;
                float pb = fB[nt][t4];
                int2 pk;
                pk.x = pack2(ysr * fA[nt][t4] + fD[nt][t4],
                             y0r * pb + ysr * fC[0][nt][t4]);
                pk.y = pack2(y1r * pb + ysr * fC[1][nt][t4],
                             y2r * pb + ysr * fC[2][nt][t4]);
                *(int2*)(Msg + row + col * 4) = pk;
            }
        }

        // ---- rotate pipeline
        tile = tn;
        if (hasN) {
            xs8 = xsN; xv8[0] = xvxN; xv8[1] = xvyN; xv8[2] = xvzN;
            dt8 = dot3(xvxN, xvyN, xvzN, eaN);
#pragma unroll
            for (int j = 0; j < 8; ++j) efC[j] = efN[j];
            eaC = eaN;
            snd1 = snd2;
        }
    }
}

// ---------------------------------------------------------------------------
// Node kernel: gather via elist (deg from cnt). 16 unconditional Msg-row
// loads with clamped edge ids + predicated accumulate; R10's interleaved
// row layout -> same de-interleaving sM fill as R10.
// ---------------------------------------------------------------------------
__global__ __launch_bounds__(256) void node_kernel(
    const float* __restrict__ node_attrs, const unsigned short* __restrict__ Msg,
    const int* __restrict__ cnt, const int* __restrict__ elist,
    const unsigned short* __restrict__ WB0, const unsigned short* __restrict__ WB1,
    float* __restrict__ out) {
    __shared__ float sM[16][129];
    __shared__ float sAt[16][17];
    int n0 = blockIdx.x * 16;

    int nl = threadIdx.x >> 4;
    int cg = threadIdx.x & 15;
    int n = n0 + nl;
    int deg = cnt[n];
    const int* el = elist + n * SLOTS;
    float acc[8];
#pragma unroll
    for (int j = 0; j < 8; ++j) acc[j] = 0.f;
    {
        int4 e4[4];
#pragma unroll
        for (int i = 0; i < 4; ++i) e4[i] = *(const int4*)(el + i * 4);
        const int* ei = (const int*)e4;
        f32x4 r[16];
#pragma unroll
        for (int i = 0; i < 16; ++i) {
            int e = (i < deg) ? ei[i] : 0;   // clamp: unwritten slots are poison
            r[i] = *(const f32x4*)(Msg + (size_t)e * 128 + cg * 8);
        }
#pragma unroll
        for (int i = 0; i < 16; ++i) {
            if (i < deg) {
                const unsigned short* us = (const unsigned short*)&r[i];
#pragma unroll
                for (int j = 0; j < 8; ++j) acc[j] += f16f(us[j]);
            }
        }
    }
    for (int s = 16; s < deg; ++s) {   // rare deg>16 tail
        int e = el[s];
        f32x4 raw = *(const f32x4*)(Msg + (size_t)e * 128 + cg * 8);
        const unsigned short* us = (const unsigned short*)&raw;
#pragma unroll
        for (int j = 0; j < 8; ++j) acc[j] += f16f(us[j]);
    }
#pragma unroll
    for (int j = 0; j < 8; ++j)
        sM[nl][(j & 3) * 32 + cg * 2 + (j >> 2)] = acc[j];
    sAt[nl][cg] = node_attrs[n * 16 + cg];
    __syncthreads();

    int p = threadIdx.x >> 6;
    int lane = threadIdx.x & 63;
    int m = lane & 15, q = lane >> 4;
    const unsigned short* WB = (p == 0) ? WB0 : WB1;
    int chb = p * 32;
    f32x4 z = {0.f, 0.f, 0.f, 0.f};
    f32x4 D0 = z, D1 = z;
#pragma unroll
    for (int ks = 0; ks < 16; ++ks) {
        int kb = ks * 32 + q * 8;
        float t[8];
#pragma unroll
        for (int j = 0; j < 8; ++j) {
            int k = kb + j;
            t[j] = sM[m][chb + (k >> 4)] * sAt[m][k & 15];
        }
        f16x8 a = cvt8h(t);
        f16x8 b0 = *(const f16x8*)(WB + (ks * 64 + lane) * 8);
        f16x8 b1 = *(const f16x8*)(WB + ((16 + ks) * 64 + lane) * 8);
        D0 = __builtin_amdgcn_mfma_f32_16x16x32_f16(a, b0, D0, 0, 0, 0);
        D1 = __builtin_amdgcn_mfma_f32_16x16x32_f16(a, b1, D1, 0, 0, 0);
    }

#pragma unroll
    for (int t4 = 0; t4 < 4; ++t4) {
        int nl2 = q * 4 + t4;
        int nn = n0 + nl2;
        if (p == 0) {
            out[nn * 128 + m]      = sM[nl2][m] + D0[t4];
            out[nn * 128 + 16 + m] = sM[nl2][16 + m] + D1[t4];
        } else {
            int i = p - 1;
            out[nn * 128 + 32 + m * 3 + i]        = sM[nl2][chb + m] + D0[t4];
            out[nn * 128 + 32 + (16 + m) * 3 + i] = sM[nl2][chb + 16 + m] + D1[t4];
        }
    }
}

extern "C" void kernel_launch(void* const* d_in, const int* in_sizes, int n_in,
                              void* d_out, int out_size, void* d_ws, size_t ws_size,
                              hipStream_t stream) {
    (void)in_sizes; (void)n_in; (void)out_size; (void)ws_size;
    const float* node_attrs = (const float*)d_in[0];
    const float* node_feats = (const float*)d_in[1];
    const float* edge_attrs = (const float*)d_in[2];
    const float* edge_feats = (const float*)d_in[3];
    const int*   edge_index = (const int*)d_in[4];
    const float* Wgen = (const float*)d_in[5];
    const float* L1s  = (const float*)d_in[6];
    const float* L1v  = (const float*)d_in[7];
    const float* WS0  = (const float*)d_in[8];
    const float* WS1  = (const float*)d_in[9];
    const float* L2s  = (const float*)d_in[10];
    const float* L2v  = (const float*)d_in[11];
    float* out = (float*)d_out;
    char* ws = (char*)d_ws;

    // Msg: N_EDGES rows x 128 f16 (edge-indexed, interleaved) = 25,600,000 B
    unsigned short* Msg = (unsigned short*)ws;
    unsigned short* Wc  = (unsigned short*)(ws + 25600000);    //    65,536
    unsigned short* WB0 = (unsigned short*)(ws + 25665536);    //    32,768
    unsigned short* WB1 = (unsigned short*)(ws + 25698304);    //    32,768
    int* cnt   = (int*)(ws + 25731072);                        //    40,000
    int* elist = (int*)(ws + 25771072);                        // 1,600,000
    unsigned short* xf = (unsigned short*)(ws + 27371072);     // 2,560,000

    prep_kernel<<<64, 1024, 0, stream>>>(Wgen, L1s, L1v, WS0, WS1, L2s, L2v,
                                         node_feats, Wc, WB0, WB1, xf, cnt);
    edge_kernel<<<512, 256, 0, stream>>>(xf, edge_attrs, edge_feats,
                                         edge_index, Wc, cnt, elist, Msg);
    node_kernel<<<625, 256, 0, stream>>>(node_attrs, Msg, cnt, elist,
                                         WB0, WB1, out);
}

// Round 13
// 127.622 us; speedup vs baseline: 1.0678x; 1.0453x over previous
//
#include <hip/hip_runtime.h>

#define N_NODES 10000
#define N_EDGES 100000
#define SLOTS 40   // max degree bound; Poisson(10), P(deg>=40) ~ 1e-12

typedef __attribute__((ext_vector_type(8))) _Float16 f16x8;
typedef __attribute__((ext_vector_type(2))) _Float16 f16x2;
typedef __attribute__((ext_vector_type(4))) float f32x4;

// __builtin_amdgcn_cvt_pkrtz returns __fp16x2; rewrap bits as _Float16x2.
static __device__ inline f16x2 pkrtz(float a, float b) {
    auto t = __builtin_amdgcn_cvt_pkrtz(a, b);
    union { decltype(t) x; f16x2 y; } u;
    u.x = t;
    return u.y;
}
static __device__ inline unsigned short f16u(float x) {
    union { _Float16 h; unsigned short s; } u;
    u.h = (_Float16)x;
    return u.s;
}
static __device__ inline float f16f(unsigned short us) {
    union { unsigned short s; _Float16 h; } u;
    u.s = us;
    return (float)u.h;
}
static __device__ inline f16x8 cvt8h(const float* f) {
    f16x8 r; f16x2* rp = (f16x2*)&r;
#pragma unroll
    for (int i = 0; i < 4; ++i) rp[i] = pkrtz(f[2 * i], f[2 * i + 1]);
    return r;
}
static __device__ inline f16x8 scale8(f16x2 h2, f16x8 x) {
    f16x8 r; f16x2* rp = (f16x2*)&r; f16x2* xp = (f16x2*)&x;
#pragma unroll
    for (int i = 0; i < 4; ++i) rp[i] = h2 * xp[i];
    return r;
}
static __device__ inline int pack2(float a, float b) {
    union { f16x2 h; int i; } u;
    u.h = pkrtz(a, b);
    return u.i;
}

// ---------------------------------------------------------------------------
// Prep kernel (fold-only): 64 blocks x 1024 threads. Tables emitted as F16.
// ---------------------------------------------------------------------------
__global__ __launch_bounds__(1024) void prep_kernel(
    const float* __restrict__ Wgen, const float* __restrict__ L1s,
    const float* __restrict__ L1v, const float* __restrict__ WS0,
    const float* __restrict__ WS1, const float* __restrict__ L2s,
    const float* __restrict__ L2v, unsigned short* __restrict__ Wc,
    unsigned short* __restrict__ WB0, unsigned short* __restrict__ WB1,
    int* __restrict__ cnt) {
    const float S = 1.0f / 128.0f;
    int tid = blockIdx.x * 1024 + threadIdx.x;   // 0..65535
    if (tid < N_NODES) cnt[tid] = 0;             // per-node slot counters
    if (tid < 32768) {
        int j = tid & 7;
        int lane = (tid >> 3) & 63;
        int ks = (tid >> 9) & 7;
        int nt = tid >> 12;
        int col = nt * 16 + (lane & 15);
        int u = (lane >> 4) * 8 + j;
        int r = ks;
        int p, c2;
        const float* M;
        float sc = S;
        if (col < 32)      { p = 0; M = L1s; c2 = col; }
        else if (col < 64) { p = 1; M = L1v; c2 = col - 32; }
        else if (col < 96) { p = 2; M = L1v; c2 = col - 64; }
        else               { p = 3; M = L1s; c2 = col - 96; sc = S * 0.57735026918962576f; }
        const float* wg = Wgen + r * 4096 + p * 1024 + u * 32;
        float acc = 0.f;
#pragma unroll
        for (int w = 0; w < 32; ++w) acc += wg[w] * M[w * 32 + c2];
        Wc[tid] = f16u(acc * sc);
    } else {
        int idx = tid - 32768;
        int table = idx >> 14;
        int r14 = idx & 16383;
        int j = r14 & 7;
        int lane = (r14 >> 3) & 63;
        int ks = (r14 >> 9) & 15;
        int k = ks * 32 + (lane >> 4) * 8 + j;
        int u = k >> 4, v = k & 15;
        int w = ((r14 >> 13) & 1) * 16 + (lane & 15);
        const float* WS = table ? WS1 : WS0;
        const float* L2 = table ? L2v : L2s;
        const float* src = WS + u * 512 + v * 32;
        float acc = 0.f;
#pragma unroll
        for (int x = 0; x < 32; ++x) acc += src[x] * L2[x * 32 + w];
        unsigned short val = f16u(acc * S);
        if (table) WB1[r14] = val; else WB0[r14] = val;
    }
}

// ---------------------------------------------------------------------------
// Edge kernel v11 (best measured config, 126.9us): F16 PACKED DATAPATH.
//  - pipeline state held as f16x8 (xs8, xv8[3], dt8); converted ONCE per tile
//    at rotate via v_cvt_pkrtz (2 vals/inst).
//  - A-frag build: 4x v_pk_mul_f16 (was 8 mul + 8 cvt).
//  - MFMA f32_16x16x32_f16 (same rate/layout as bf16).
//  - 2-deep index prefetch, sEA/sSL strips, static stride, 256 thr/512 blocks.
// ---------------------------------------------------------------------------
__global__ __launch_bounds__(256) void edge_kernel(
    const float* __restrict__ node_feats, const float* __restrict__ edge_attrs,
    const float* __restrict__ edge_feats, const int* __restrict__ edge_index,
    const unsigned short* __restrict__ Wc, int* __restrict__ cnt,
    unsigned short* __restrict__ Msg) {
    __shared__ f16x8 sW8[4096];     // 64 KB, B-fragment order (f16 bits)
    __shared__ int sSL[4][16];      // per-wave slot strip
    __shared__ f32x4 sEA[4][16];    // per-wave edge_attrs strip
    {
        const f16x8* src = (const f16x8*)Wc;
        for (int i = threadIdx.x; i < 4096; i += 256) sW8[i] = src[i];
    }
    __syncthreads();

    const int lane = threadIdx.x & 63;
    const int m = lane & 15, q = lane >> 4;
    const int wv = threadIdx.x >> 6;
    const int wave = (blockIdx.x * 256 + threadIdx.x) >> 6;
    const int stride = gridDim.x * 4;
    const int NT = N_EDGES / 16;

    int tile = wave;
    if (tile >= NT) return;

    // converted pipeline state for current tile
    f16x8 xs8, xv8[3], dt8;
    float efC[8];
    f32x4 eaC;
    int slC = 0;

    // ---- prologue: gather + convert for first tile; idx prefetch for +stride
    {
        int e = tile * 16 + m;
        int snd = edge_index[e];
        if (lane < 16) {
            int r = edge_index[N_EDGES + e];
            slC = r * SLOTS + atomicAdd(&cnt[r], 1);
        }
        const float* g = node_feats + snd * 128;
        float xs[8], xv[24];
        *(f32x4*)&xs[0] = *(const f32x4*)(g + q * 8);
        *(f32x4*)&xs[4] = *(const f32x4*)(g + q * 8 + 4);
#pragma unroll
        for (int i = 0; i < 6; ++i)
            *(f32x4*)&xv[i * 4] = *(const f32x4*)(g + 32 + q * 24 + i * 4);
        *(f32x4*)&efC[0] = *(const f32x4*)(edge_feats + e * 8);
        *(f32x4*)&efC[4] = *(const f32x4*)(edge_feats + e * 8 + 4);
        eaC = *(const f32x4*)(edge_attrs + e * 4);
        float dt[8];
        float y0 = eaC.y, y1 = eaC.z, y2 = eaC.w;
#pragma unroll
        for (int j = 0; j < 8; ++j)
            dt[j] = xv[j * 3] * y0 + xv[j * 3 + 1] * y1 + xv[j * 3 + 2] * y2;
        xs8 = cvt8h(xs);
#pragma unroll
        for (int c = 0; c < 3; ++c) {
            f16x8 r; f16x2* rp = (f16x2*)&r;
#pragma unroll
            for (int i = 0; i < 4; ++i)
                rp[i] = pkrtz(xv[(2 * i) * 3 + c], xv[(2 * i + 1) * 3 + c]);
            xv8[c] = r;
        }
        dt8 = cvt8h(dt);
    }
    int snd1 = 0, rcv1 = 0;
    {
        int t1 = tile + stride;
        if (t1 < NT) {
            int e1 = t1 * 16 + m;
            snd1 = edge_index[e1];
            if (lane < 16) rcv1 = edge_index[N_EDGES + e1];
        }
    }

    while (tile < NT) {
        const int tn = tile + stride;
        const bool hasN = tn < NT;
        const int t2 = tile + 2 * stride;
        const bool has2 = t2 < NT;

        // ---- publish current slots + edge_attrs rows to LDS strips
        if (lane < 16) {
            sSL[wv][lane] = slC;
            sEA[wv][lane] = eaC;
        }

        // ---- prefetch tile+s raw state (in-register indices, no dep wait)
        float xsN[8], xvN[24], efN[8];
        f32x4 eaN;
        int slN = 0;
        if (hasN) {
            int en = tn * 16 + m;
            if (lane < 16) slN = rcv1 * SLOTS + atomicAdd(&cnt[rcv1], 1);
            const float* gN = node_feats + snd1 * 128;
            *(f32x4*)&xsN[0] = *(const f32x4*)(gN + q * 8);
            *(f32x4*)&xsN[4] = *(const f32x4*)(gN + q * 8 + 4);
#pragma unroll
            for (int i = 0; i < 6; ++i)
                *(f32x4*)&xvN[i * 4] = *(const f32x4*)(gN + 32 + q * 24 + i * 4);
            *(f32x4*)&efN[0] = *(const f32x4*)(edge_feats + en * 8);
            *(f32x4*)&efN[4] = *(const f32x4*)(edge_feats + en * 8 + 4);
            eaN = *(const f32x4*)(edge_attrs + en * 4);
        }

        // ---- prefetch tile+2s indices
        int snd2 = 0, rcv2 = 0;
        if (has2) {
            int e2 = t2 * 16 + m;
            snd2 = edge_index[e2];
            if (lane < 16) rcv2 = edge_index[N_EDGES + e2];
        }

        // ---- compute current tile (f16 packed A-builds)
        f32x4 z = {0.f, 0.f, 0.f, 0.f};
        f32x4 fA[2] = {z, z}, fB[2] = {z, z}, fD[2] = {z, z};
        f32x4 fC[3][2] = {{z, z}, {z, z}, {z, z}};

#pragma unroll
        for (int ks = 0; ks < 8; ++ks) {
            _Float16 h = (_Float16)efC[ks];
            f16x2 h2 = {h, h};
            {
                f16x8 a = scale8(h2, xs8);
                fA[0] = __builtin_amdgcn_mfma_f32_16x16x32_f16(a, sW8[(0 * 8 + ks) * 64 + lane], fA[0], 0, 0, 0);
                fA[1] = __builtin_amdgcn_mfma_f32_16x16x32_f16(a, sW8[(1 * 8 + ks) * 64 + lane], fA[1], 0, 0, 0);
                fB[0] = __builtin_amdgcn_mfma_f32_16x16x32_f16(a, sW8[(2 * 8 + ks) * 64 + lane], fB[0], 0, 0, 0);
                fB[1] = __builtin_amdgcn_mfma_f32_16x16x32_f16(a, sW8[(3 * 8 + ks) * 64 + lane], fB[1], 0, 0, 0);
            }
            {
                f16x8 bc0 = sW8[(4 * 8 + ks) * 64 + lane];
                f16x8 bc1 = sW8[(5 * 8 + ks) * 64 + lane];
#pragma unroll
                for (int c = 0; c < 3; ++c) {
                    f16x8 a = scale8(h2, xv8[c]);
                    fC[c][0] = __builtin_amdgcn_mfma_f32_16x16x32_f16(a, bc0, fC[c][0], 0, 0, 0);
                    fC[c][1] = __builtin_amdgcn_mfma_f32_16x16x32_f16(a, bc1, fC[c][1], 0, 0, 0);
                }
            }
            {
                f16x8 a = scale8(h2, dt8);
                fD[0] = __builtin_amdgcn_mfma_f32_16x16x32_f16(a, sW8[(6 * 8 + ks) * 64 + lane], fD[0], 0, 0, 0);
                fD[1] = __builtin_amdgcn_mfma_f32_16x16x32_f16(a, sW8[(7 * 8 + ks) * 64 + lane], fD[1], 0, 0, 0);
            }
        }

        // ---- epilogue: per-lane rows q*4+t4; slots+attrs via ds_read_b128
        int4 sl4 = *(const int4*)&sSL[wv][q * 4];
        const int slR[4] = {sl4.x, sl4.y, sl4.z, sl4.w};
#pragma unroll
        for (int t4 = 0; t4 < 4; ++t4) {
            f32x4 ea4 = sEA[wv][q * 4 + t4];
            float ysr = ea4.x, y0r = ea4.y, y1r = ea4.z, y2r = ea4.w;
            int dr = slR[t4];
#pragma unroll
            for (int nt = 0; nt < 2; ++nt) {
                int col = nt * 16 + m;
                float pb = fB[nt][t4];
                int2 pk;
                pk.x = pack2(ysr * fA[nt][t4] + fD[nt][t4],
                             y0r * pb + ysr * fC[0][nt][t4]);
                pk.y = pack2(y1r * pb + ysr * fC[1][nt][t4],
                             y2r * pb + ysr * fC[2][nt][t4]);
                *(int2*)(Msg + (size_t)dr * 128 + col * 4) = pk;
            }
        }

        // ---- rotate pipeline: wait loads land here, convert once
        tile = tn;
        if (hasN) {
            float dtN[8];
            float y0 = eaN.y, y1 = eaN.z, y2 = eaN.w;
#pragma unroll
            for (int j = 0; j < 8; ++j)
                dtN[j] = xvN[j * 3] * y0 + xvN[j * 3 + 1] * y1 + xvN[j * 3 + 2] * y2;
            xs8 = cvt8h(xsN);
#pragma unroll
            for (int c = 0; c < 3; ++c) {
                f16x8 r; f16x2* rp = (f16x2*)&r;
#pragma unroll
                for (int i = 0; i < 4; ++i)
                    rp[i] = pkrtz(xvN[(2 * i) * 3 + c], xvN[(2 * i + 1) * 3 + c]);
                xv8[c] = r;
            }
            dt8 = cvt8h(dtN);
#pragma unroll
            for (int j = 0; j < 8; ++j) efC[j] = efN[j];
            eaC = eaN;
            slC = slN;
            snd1 = snd2;
            rcv1 = rcv2;
        }
    }
}

// ---------------------------------------------------------------------------
// Fused gather + node kernel. Msg/WB f16. Gather 8-deep batched
// (avg degree 10 -> ~1 full round instead of 2.5).
// ---------------------------------------------------------------------------
__global__ __launch_bounds__(256) void node_kernel(
    const float* __restrict__ node_attrs, const unsigned short* __restrict__ Msg,
    const int* __restrict__ cnt, const unsigned short* __restrict__ WB0,
    const unsigned short* __restrict__ WB1, float* __restrict__ out) {
    __shared__ float sM[16][129];
    __shared__ float sAt[16][17];
    int n0 = blockIdx.x * 16;

    int nl = threadIdx.x >> 4;
    int cg = threadIdx.x & 15;
    int n = n0 + nl;
    int s0 = n * SLOTS;
    int s1 = s0 + cnt[n];
    float acc[8];
#pragma unroll
    for (int j = 0; j < 8; ++j) acc[j] = 0.f;
    int s = s0;
    for (; s + 7 < s1; s += 8) {
        f32x4 r[8];
#pragma unroll
        for (int i = 0; i < 8; ++i)
            r[i] = *(const f32x4*)(Msg + (size_t)(s + i) * 128 + cg * 8);
#pragma unroll
        for (int j = 0; j < 8; ++j) {
            float a = 0.f;
#pragma unroll
            for (int i = 0; i < 8; ++i)
                a += f16f(((const unsigned short*)&r[i])[j]);
            acc[j] += a;
        }
    }
    for (; s + 3 < s1; s += 4) {
        f32x4 r0 = *(const f32x4*)(Msg + (size_t)(s + 0) * 128 + cg * 8);
        f32x4 r1 = *(const f32x4*)(Msg + (size_t)(s + 1) * 128 + cg * 8);
        f32x4 r2 = *(const f32x4*)(Msg + (size_t)(s + 2) * 128 + cg * 8);
        f32x4 r3 = *(const f32x4*)(Msg + (size_t)(s + 3) * 128 + cg * 8);
        const unsigned short* u0 = (const unsigned short*)&r0;
        const unsigned short* u1 = (const unsigned short*)&r1;
        const unsigned short* u2 = (const unsigned short*)&r2;
        const unsigned short* u3 = (const unsigned short*)&r3;
#pragma unroll
        for (int j = 0; j < 8; ++j)
            acc[j] += (f16f(u0[j]) + f16f(u1[j])) + (f16f(u2[j]) + f16f(u3[j]));
    }
    for (; s < s1; ++s) {
        f32x4 raw = *(const f32x4*)(Msg + (size_t)s * 128 + cg * 8);
        const unsigned short* us = (const unsigned short*)&raw;
#pragma unroll
        for (int j = 0; j < 8; ++j) acc[j] += f16f(us[j]);
    }
#pragma unroll
    for (int j = 0; j < 8; ++j)
        sM[nl][(j & 3) * 32 + cg * 2 + (j >> 2)] = acc[j];
    sAt[nl][cg] = node_attrs[n * 16 + cg];
    __syncthreads();

    int p = threadIdx.x >> 6;
    int lane = threadIdx.x & 63;
    int m = lane & 15, q = lane >> 4;
    const unsigned short* WB = (p == 0) ? WB0 : WB1;
    int chb = p * 32;
    f32x4 z = {0.f, 0.f, 0.f, 0.f};
    f32x4 D0 = z, D1 = z;
#pragma unroll
    for (int ks = 0; ks < 16; ++ks) {
        int kb = ks * 32 + q * 8;
        float t[8];
#pragma unroll
        for (int j = 0; j < 8; ++j) {
            int k = kb + j;
            t[j] = sM[m][chb + (k >> 4)] * sAt[m][k & 15];
        }
        f16x8 a = cvt8h(t);
        f16x8 b0 = *(const f16x8*)(WB + (ks * 64 + lane) * 8);
        f16x8 b1 = *(const f16x8*)(WB + ((16 + ks) * 64 + lane) * 8);
        D0 = __builtin_amdgcn_mfma_f32_16x16x32_f16(a, b0, D0, 0, 0, 0);
        D1 = __builtin_amdgcn_mfma_f32_16x16x32_f16(a, b1, D1, 0, 0, 0);
    }

#pragma unroll
    for (int t4 = 0; t4 < 4; ++t4) {
        int nl2 = q * 4 + t4;
        int nn = n0 + nl2;
        if (p == 0) {
            out[nn * 128 + m]      = sM[nl2][m] + D0[t4];
            out[nn * 128 + 16 + m] = sM[nl2][16 + m] + D1[t4];
        } else {
            int i = p - 1;
            out[nn * 128 + 32 + m * 3 + i]        = sM[nl2][chb + m] + D0[t4];
            out[nn * 128 + 32 + (16 + m) * 3 + i] = sM[nl2][chb + 16 + m] + D1[t4];
        }
    }
}

extern "C" void kernel_launch(void* const* d_in, const int* in_sizes, int n_in,
                              void* d_out, int out_size, void* d_ws, size_t ws_size,
                              hipStream_t stream) {
    (void)in_sizes; (void)n_in; (void)out_size; (void)ws_size;
    const float* node_attrs = (const float*)d_in[0];
    const float* node_feats = (const float*)d_in[1];
    const float* edge_attrs = (const float*)d_in[2];
    const float* edge_feats = (const float*)d_in[3];
    const int*   edge_index = (const int*)d_in[4];
    const float* Wgen = (const float*)d_in[5];
    const float* L1s  = (const float*)d_in[6];
    const float* L1v  = (const float*)d_in[7];
    const float* WS0  = (const float*)d_in[8];
    const float* WS1  = (const float*)d_in[9];
    const float* L2s  = (const float*)d_in[10];
    const float* L2v  = (const float*)d_in[11];
    float* out = (float*)d_out;
    char* ws = (char*)d_ws;

    // Msg: N_NODES*SLOTS rows x 128 f16 = 102,400,000 B (ws is 256 MiB)
    unsigned short* Msg = (unsigned short*)ws;
    unsigned short* Wc  = (unsigned short*)(ws + 102400000);   // 65,536
    unsigned short* WB0 = (unsigned short*)(ws + 102465536);   // 32,768
    unsigned short* WB1 = (unsigned short*)(ws + 102498304);   // 32,768
    int* cnt = (int*)(ws + 102531072);                         // 10000 ints

    prep_kernel<<<64, 1024, 0, stream>>>(Wgen, L1s, L1v, WS0, WS1, L2s, L2v,
                                         Wc, WB0, WB1, cnt);
    edge_kernel<<<512, 256, 0, stream>>>(node_feats, edge_attrs, edge_feats,
                                         edge_index, Wc, cnt, Msg);
    node_kernel<<<625, 256, 0, stream>>>(node_attrs, Msg, cnt, WB0, WB1, out);
}